// Round 1
// baseline (166.889 us; speedup 1.0000x reference)
//
#include <hip/hip_runtime.h>

#define IN_CH   16
#define OUT_CH  64
#define EXP_CH  4096
#define SET_LEN 64
#define BB      8
#define HH      56
#define WW      56
#define TH      4               // rows per tile
#define NTILES  (HH / TH)       // 14
#define LROW    58              // (WW + 2) halo columns
#define LDS_X   (IN_CH * (TH + 2) * LROW)

__global__ __launch_bounds__(256, 4)
void rptn_fused_kernel(const float* __restrict__ x,
                       const float* __restrict__ w,
                       const float* __restrict__ bias,
                       const int*   __restrict__ idx,
                       float*       __restrict__ out) {
    const int oc   = blockIdx.x;   // fastest-varying -> same x tile reused 64x in L2
    const int tile = blockIdx.y;
    const int b    = blockIdx.z;
    const int tid  = threadIdx.x;

    __shared__ float s_x[LDS_X];
    __shared__ int   s_cnt[IN_CH];
    __shared__ int   s_pos[IN_CH];
    __shared__ int   s_eord[SET_LEN];

    // ---- counting-sort set entries by source channel (e >> 8) ----
    if (tid < IN_CH) s_cnt[tid] = 0;
    __syncthreads();

    int my_e = 0, my_c = 0;
    if (tid < SET_LEN) {
        my_e = idx[oc * SET_LEN + tid];
        my_c = my_e >> 8;                // group = e / (EXP_CH/IN_CH) = e / 256
        atomicAdd(&s_cnt[my_c], 1);
    }

    // ---- stage x tile (+1 halo ring, zero-padded) into LDS ----
    const int    r0 = tile * TH;
    const float* xb = x + (size_t)b * IN_CH * HH * WW;
    for (int i = tid; i < LDS_X; i += 256) {
        int c   = i / ((TH + 2) * LROW);
        int rem = i - c * ((TH + 2) * LROW);
        int r   = rem / LROW;
        int col = rem - r * LROW;
        int gr  = r0 - 1 + r;
        int gc  = col - 1;
        float v = 0.0f;
        if ((unsigned)gr < (unsigned)HH && (unsigned)gc < (unsigned)WW)
            v = xb[(c * HH + gr) * WW + gc];
        s_x[i] = v;
    }
    __syncthreads();

    if (tid == 0) {
        int run = 0;
        for (int c = 0; c < IN_CH; ++c) { s_pos[c] = run; run += s_cnt[c]; }
    }
    __syncthreads();

    if (tid < SET_LEN) {
        int p = atomicAdd(&s_pos[my_c], 1);
        s_eord[p] = my_e;
    }
    __syncthreads();

    // ---- per-pixel fused conv + bias + running max ----
    const int tx  = tid & 63;           // column within row (wave = one row)
    const int ty  = tid >> 6;           // row within tile
    const int txr = (tx < WW) ? tx : 0; // clamp inactive lanes for safe LDS reads

    float acc  = -__builtin_inff();
    int   base = 0;
    for (int c = 0; c < IN_CH; ++c) {
        const int cnt = __builtin_amdgcn_readfirstlane(s_cnt[c]);
        if (cnt > 0) {
            const float* sp = &s_x[(c * (TH + 2) + ty) * LROW + txr];
            // load 3x3 neighborhood once per channel, reuse for all entries
            const float n00 = sp[0],        n01 = sp[1],        n02 = sp[2];
            const float n10 = sp[LROW],     n11 = sp[LROW + 1], n12 = sp[LROW + 2];
            const float n20 = sp[2 * LROW], n21 = sp[2*LROW+1], n22 = sp[2*LROW+2];
            for (int j = 0; j < cnt; ++j) {
                const int e = __builtin_amdgcn_readfirstlane(s_eord[base + j]);
                const float* wp = w + e * 9;       // uniform -> scalar loads
                float p0 = wp[0] * n00 + wp[1] * n01 + wp[2] * n02;
                float p1 = wp[3] * n10 + wp[4] * n11 + wp[5] * n12;
                float p2 = wp[6] * n20 + wp[7] * n21 + wp[8] * n22;
                float v  = bias[e] + p0 + p1 + p2;
                acc = fmaxf(acc, v);
            }
        }
        base += cnt;
    }

    if (tx < WW) {
        out[(((size_t)b * OUT_CH + oc) * HH + (r0 + ty)) * WW + tx] = acc;
    }
}

extern "C" void kernel_launch(void* const* d_in, const int* in_sizes, int n_in,
                              void* d_out, int out_size, void* d_ws, size_t ws_size,
                              hipStream_t stream) {
    const float* x    = (const float*)d_in[0];
    const float* w    = (const float*)d_in[1];
    const float* bias = (const float*)d_in[2];
    const int*   idx  = (const int*)d_in[3];
    float*       out  = (float*)d_out;

    dim3 grid(OUT_CH, NTILES, BB);   // oc fastest -> x tile L2 reuse
    dim3 block(256);
    rptn_fused_kernel<<<grid, block, 0, stream>>>(x, w, bias, idx, out);
}